// Round 2
// baseline (473.934 us; speedup 1.0000x reference)
//
#include <hip/hip_runtime.h>
#include <hip/hip_cooperative_groups.h>
#include <stdint.h>

namespace cg = cooperative_groups;

// Problem constants (fixed by reference setup_inputs)
#define BB 8
#define SS 2048
#define DD 2048
#define EE 8
#define SCH 128     // superchunks per batch
#define SROWS 16    // rows per superchunk (SS / SCH)
#define NBLK (BB * SCH)   // 1024 blocks = 4 blocks/CU on 256 CUs -> co-resident

typedef float f4 __attribute__((ext_vector_type(4)));

// Fused cooperative kernel.
// Phase 1 (all 1024 blocks): stream 16 rows of x, accumulate per-thread column
//   sums; epilogue dots with W (L2-hot) -> 9 partials per block -> pbuf.
// grid.sync()  (device-scope release/acquire across XCDs)
// Phase 2 (block 0 only): reduce 1024 records, W row stats, scores, softmax,
//   top-2, outputs.
__global__ __launch_bounds__(256, 4) void k_fused(const float* __restrict__ x,
                                                  const float* __restrict__ W,
                                                  const float* __restrict__ gain,
                                                  const float* __restrict__ istd,
                                                  const float* __restrict__ noise,
                                                  float* __restrict__ pbuf,
                                                  float* __restrict__ out) {
    const int t = threadIdx.x;
    const int bid = blockIdx.x;
    const int b = bid >> 7;              // / SCH
    const int sc = bid & (SCH - 1);
    const int d0 = t * 8;                // 256 threads * 8 floats = full D row

    const float* xp = x + ((size_t)b * SS + (size_t)sc * SROWS) * DD + d0;

    // ---- Phase 1: column sums over SROWS rows (memory-bound hot loop)
    float xsum[8] = {0.f, 0.f, 0.f, 0.f, 0.f, 0.f, 0.f, 0.f};
#pragma unroll 8
    for (int r = 0; r < SROWS; ++r) {
        f4 xa = *(const f4*)(xp + (size_t)r * DD);
        f4 xb = *(const f4*)(xp + (size_t)r * DD + 4);
#pragma unroll
        for (int j = 0; j < 4; ++j) { xsum[j] += xa[j]; xsum[4 + j] += xb[j]; }
    }

    // Epilogue: 9 partials = 8 expert dots (W from L2) + total x sum
    float vals[9];
    float xtot = 0.f;
#pragma unroll
    for (int j = 0; j < 8; ++j) xtot += xsum[j];
#pragma unroll
    for (int e = 0; e < 8; ++e) {
        f4 wa = *(const f4*)(W + e * DD + d0);
        f4 wb = *(const f4*)(W + e * DD + d0 + 4);
        float acc = 0.f;
#pragma unroll
        for (int j = 0; j < 4; ++j) acc = fmaf(xsum[j], wa[j], acc);
#pragma unroll
        for (int j = 0; j < 4; ++j) acc = fmaf(xsum[4 + j], wb[j], acc);
        vals[e] = acc;
    }
    vals[8] = xtot;

    // wave-level butterfly reduce of 9 values
#pragma unroll
    for (int off = 32; off >= 1; off >>= 1) {
#pragma unroll
        for (int j = 0; j < 9; ++j) vals[j] += __shfl_xor(vals[j], off, 64);
    }

    __shared__ float lw[4][9];
    const int lane = t & 63, wid = t >> 6;
    if (lane == 0) {
#pragma unroll
        for (int j = 0; j < 9; ++j) lw[wid][j] = vals[j];
    }
    __syncthreads();
    if (t < 9) {
        pbuf[bid * 9 + t] = lw[0][t] + lw[1][t] + lw[2][t] + lw[3][t];
    }

    __threadfence();          // device-scope release of pbuf writes
    cg::this_grid().sync();   // grid barrier + memory ordering

    if (bid != 0) return;

    // ---- Phase 2 (block 0): finish
    const int l = t & 31;
    const int g = t >> 5;   // group 0..7: batch idx in phase A, expert idx in phase B

    __shared__ float sdot[BB][9];
    __shared__ float smean[EE], sscale[EE];

    // Phase A: thread t owns records [t*4, t*4+4) (36 floats = 9 f4), all in
    // batch g = t>>5 (128 records per batch); tree-reduce across 32-lane group.
    float sums[9] = {0.f, 0.f, 0.f, 0.f, 0.f, 0.f, 0.f, 0.f, 0.f};
    {
        const f4* pa = (const f4*)(pbuf + (size_t)t * 36);
#pragma unroll
        for (int i = 0; i < 9; ++i) {
            f4 v = pa[i];
#pragma unroll
            for (int j = 0; j < 4; ++j) sums[(i * 4 + j) % 9] += v[j];
        }
    }
#pragma unroll
    for (int off = 16; off >= 1; off >>= 1) {
#pragma unroll
        for (int j = 0; j < 9; ++j) sums[j] += __shfl_xor(sums[j], off, 64);
    }
    if (l < 9) sdot[g][l] = sums[l];

    // Phase B: W row stats (mean, unbiased std + EPS, keep_init scale)
    {
        float s = 0.f, q = 0.f;
        const f4* wp = (const f4*)(W + (size_t)g * DD + l * 64);
#pragma unroll
        for (int i = 0; i < 16; ++i) {
            f4 v = wp[i];
#pragma unroll
            for (int j = 0; j < 4; ++j) { s += v[j]; q = fmaf(v[j], v[j], q); }
        }
#pragma unroll
        for (int off = 16; off >= 1; off >>= 1) {
            s += __shfl_xor(s, off, 64);
            q += __shfl_xor(q, off, 64);
        }
        if (l == 0) {
            const float mean = s / (float)DD;
            float var = (q - (float)DD * mean * mean) / (float)(DD - 1);
            var = fmaxf(var, 0.f);
            const float stdv = sqrtf(var) + 1e-5f;   // torch-style unbiased std + EPS
            smean[g] = mean;
            sscale[g] = istd[g] / stdv * gain[g];
        }
    }
    __syncthreads();

    // Phase C: one thread per batch row
    if (t < BB) {
        const int bb = t;
        const float xtot2 = sdot[bb][8];
        float p[EE];
        float m = -1e30f;
#pragma unroll
        for (int e = 0; e < EE; ++e) {
            float scv = sscale[e] * (sdot[bb][e] - smean[e] * xtot2) * (1.f / (float)SS)
                      + noise[bb * EE + e];
            p[e] = scv;
            m = fmaxf(m, scv);
        }
        float sum = 0.f;
#pragma unroll
        for (int e = 0; e < EE; ++e) { p[e] = __expf(p[e] - m); sum += p[e]; }
        const float inv = 1.f / sum;
#pragma unroll
        for (int e = 0; e < EE; ++e) p[e] *= inv;

        // top-2, ties -> lowest index first (strict >, ascending scan)
        int i1 = 0;
#pragma unroll
        for (int e = 1; e < EE; ++e) if (p[e] > p[i1]) i1 = e;
        int i2 = (i1 == 0) ? 1 : 0;
#pragma unroll
        for (int e = 0; e < EE; ++e) if (e != i1 && p[e] > p[i2]) i2 = e;

        // combine tensor [B,E]
#pragma unroll
        for (int e = 0; e < EE; ++e) {
            float v = (e == i1) ? p[i1] : ((e == i2) ? p[i2] : 0.f);
            out[bb * EE + e] = v;
        }
        // indices [B,2] as numeric values
        out[64 + bb * 2 + 0] = (float)i1;
        out[64 + bb * 2 + 1] = (float)i2;
        // topk gate scores [B,2]
        out[80 + bb * 2 + 0] = p[i1];
        out[80 + bb * 2 + 1] = p[i2];
    }
}

extern "C" void kernel_launch(void* const* d_in, const int* in_sizes, int n_in,
                              void* d_out, int out_size, void* d_ws, size_t ws_size,
                              hipStream_t stream) {
    const float* x     = (const float*)d_in[0];
    const float* W     = (const float*)d_in[1];
    const float* gain  = (const float*)d_in[2];
    const float* istd  = (const float*)d_in[3];
    const float* noise = (const float*)d_in[4];
    // d_in[5] = top_k (==2) — hardcoded per reference.

    float* pbuf = (float*)d_ws;          // NBLK*9 floats = 36 KB
    float* out  = (float*)d_out;         // 96 fp32

    void* args[7];
    args[0] = (void*)&x;
    args[1] = (void*)&W;
    args[2] = (void*)&gain;
    args[3] = (void*)&istd;
    args[4] = (void*)&noise;
    args[5] = (void*)&pbuf;
    args[6] = (void*)&out;

    hipLaunchCooperativeKernel(reinterpret_cast<void*>(k_fused),
                               dim3(NBLK), dim3(256), args, 0, stream);
}

// Round 3
// 200.692 us; speedup vs baseline: 2.3615x; 2.3615x over previous
//
#include <hip/hip_runtime.h>
#include <stdint.h>

// Problem constants (fixed by reference setup_inputs)
#define BB 8
#define SS 2048
#define DD 2048
#define EE 8
#define CHUNKS 256
#define ROWS 8              // SS / CHUNKS
#define NBLK (BB * CHUNKS)  // 2048 blocks
#define AUX  (NBLK * 9)     // float offset of W-stat aux region in pbuf

typedef float f4 __attribute__((ext_vector_type(4)));

// Kernel 1: stream x (fp32). Per block = one (b, chunk of 8 rows).
// Hot loop: software-pipelined column sums (8 f4 loads in flight per group).
// Epilogue: dot with W (L2-hot) -> 9 partials; block 0 additionally reduces
// per-expert sum/sumsq of W (it already holds all of W in fragments) -> aux.
__global__ __launch_bounds__(256) void k_partial(const float* __restrict__ x,
                                                 const float* __restrict__ W,
                                                 float* __restrict__ pout) {
    const int t = threadIdx.x;
    const int bid = blockIdx.x;
    const int b = bid >> 8;              // / CHUNKS
    const int chunk = bid & (CHUNKS - 1);
    const int d0 = t * 8;                // 256 threads * 8 floats = full D row

    const float* xp = x + ((size_t)b * SS + (size_t)chunk * ROWS) * DD + d0;

    // ---- column sums over 8 rows, 2 groups of 4 rows (8 loads in flight)
    f4 s0 = {0.f, 0.f, 0.f, 0.f}, s1 = {0.f, 0.f, 0.f, 0.f};
#pragma unroll
    for (int g = 0; g < 2; ++g) {
        const float* p = xp + (size_t)g * 4 * DD;
        f4 a0 = *(const f4*)(p);
        f4 b0 = *(const f4*)(p + 4);
        f4 a1 = *(const f4*)(p + DD);
        f4 b1 = *(const f4*)(p + DD + 4);
        f4 a2 = *(const f4*)(p + 2 * DD);
        f4 b2 = *(const f4*)(p + 2 * DD + 4);
        f4 a3 = *(const f4*)(p + 3 * DD);
        f4 b3 = *(const f4*)(p + 3 * DD + 4);
        s0 += a0; s1 += b0;
        s0 += a1; s1 += b1;
        s0 += a2; s1 += b2;
        s0 += a3; s1 += b3;
    }

    // ---- epilogue: 9 partials = 8 expert dots + total x sum
    float vals[9];
    vals[8] = s0[0] + s0[1] + s0[2] + s0[3] + s1[0] + s1[1] + s1[2] + s1[3];
    float wsv[8], wqv[8];   // per-expert W sum / sumsq partials (block 0 uses)
#pragma unroll
    for (int e = 0; e < 8; ++e) {
        f4 wa = *(const f4*)(W + e * DD + d0);
        f4 wb = *(const f4*)(W + e * DD + d0 + 4);
        float acc = 0.f;
#pragma unroll
        for (int j = 0; j < 4; ++j) acc = fmaf(s0[j], wa[j], acc);
#pragma unroll
        for (int j = 0; j < 4; ++j) acc = fmaf(s1[j], wb[j], acc);
        vals[e] = acc;
        float ws = wa[0] + wa[1] + wa[2] + wa[3] + wb[0] + wb[1] + wb[2] + wb[3];
        float wq = 0.f;
#pragma unroll
        for (int j = 0; j < 4; ++j) wq = fmaf(wa[j], wa[j], wq);
#pragma unroll
        for (int j = 0; j < 4; ++j) wq = fmaf(wb[j], wb[j], wq);
        wsv[e] = ws;
        wqv[e] = wq;
    }

    // ---- wave butterfly reduce of the 9 partials, then cross-wave via LDS
#pragma unroll
    for (int off = 32; off >= 1; off >>= 1) {
#pragma unroll
        for (int j = 0; j < 9; ++j) vals[j] += __shfl_xor(vals[j], off, 64);
    }

    __shared__ float lw[4][9];
    const int lane = t & 63, wid = t >> 6;
    if (lane == 0) {
#pragma unroll
        for (int j = 0; j < 9; ++j) lw[wid][j] = vals[j];
    }
    __syncthreads();
    if (t < 9) {
        pout[bid * 9 + t] = lw[0][t] + lw[1][t] + lw[2][t] + lw[3][t];
    }

    // ---- block 0 only: finish W row stats (covers all 2048 cols x 8 experts)
    if (bid == 0) {
#pragma unroll
        for (int off = 32; off >= 1; off >>= 1) {
#pragma unroll
            for (int e = 0; e < 8; ++e) {
                wsv[e] += __shfl_xor(wsv[e], off, 64);
                wqv[e] += __shfl_xor(wqv[e], off, 64);
            }
        }
        __shared__ float lw2[4][16];
        if (lane == 0) {
#pragma unroll
            for (int e = 0; e < 8; ++e) {
                lw2[wid][e] = wsv[e];
                lw2[wid][8 + e] = wqv[e];
            }
        }
        __syncthreads();
        if (t < 16) {
            pout[AUX + t] = lw2[0][t] + lw2[1][t] + lw2[2][t] + lw2[3][t];
        }
    }
}

// Kernel 2: single block. W stats arrive pre-reduced in aux (16 floats):
// Phase A: reduce 2048 partial records (9 floats each, 72 KB): thread t owns
//          8 consecutive records (18 f4 loads, same batch g = t>>5),
//          then 5-stage shfl_xor tree across its 32-thread group.
// Phase C: 8 threads: scores -> softmax -> top2 -> outputs.
__global__ __launch_bounds__(256) void k_finish(const float* __restrict__ pin,
                                                const float* __restrict__ gain,
                                                const float* __restrict__ istd,
                                                const float* __restrict__ noise,
                                                float* __restrict__ out) {
    const int t = threadIdx.x;
    const int l = t & 31;
    const int g = t >> 5;   // batch index in phase A

    __shared__ float sdot[BB][9];
    __shared__ float smean[EE], sscale[EE];

    // ---- W stats from aux (already fully reduced by k_partial block 0)
    if (t < EE) {
        const float s = pin[AUX + t];
        const float q = pin[AUX + 8 + t];
        const float mean = s / (float)DD;
        float var = (q - (float)DD * mean * mean) / (float)(DD - 1);
        var = fmaxf(var, 0.f);
        const float stdv = sqrtf(var) + 1e-5f;   // torch-style unbiased std + EPS
        smean[t] = mean;
        sscale[t] = istd[t] / stdv * gain[t];
    }

    // ---- Phase A
    float sums[9] = {0.f, 0.f, 0.f, 0.f, 0.f, 0.f, 0.f, 0.f, 0.f};
    {
        const f4* pa = (const f4*)(pin + (size_t)t * 72);
#pragma unroll
        for (int i = 0; i < 18; ++i) {
            f4 v = pa[i];
#pragma unroll
            for (int j = 0; j < 4; ++j) sums[(i * 4 + j) % 9] += v[j];
        }
    }
#pragma unroll
    for (int off = 16; off >= 1; off >>= 1) {
#pragma unroll
        for (int j = 0; j < 9; ++j) sums[j] += __shfl_xor(sums[j], off, 64);
    }
    if (l < 9) sdot[g][l] = sums[l];
    __syncthreads();

    // ---- Phase C: one thread per batch row
    if (t < BB) {
        const int b = t;
        const float xtot = sdot[b][8];
        float p[EE];
        float m = -1e30f;
#pragma unroll
        for (int e = 0; e < EE; ++e) {
            float sc = sscale[e] * (sdot[b][e] - smean[e] * xtot) * (1.f / (float)SS)
                     + noise[b * EE + e];
            p[e] = sc;
            m = fmaxf(m, sc);
        }
        float sum = 0.f;
#pragma unroll
        for (int e = 0; e < EE; ++e) { p[e] = __expf(p[e] - m); sum += p[e]; }
        const float inv = 1.f / sum;
#pragma unroll
        for (int e = 0; e < EE; ++e) p[e] *= inv;

        // top-2, ties -> lowest index first (strict >, ascending scan)
        int i1 = 0;
#pragma unroll
        for (int e = 1; e < EE; ++e) if (p[e] > p[i1]) i1 = e;
        int i2 = (i1 == 0) ? 1 : 0;
#pragma unroll
        for (int e = 0; e < EE; ++e) if (e != i1 && p[e] > p[i2]) i2 = e;

        // combine tensor [B,E]
#pragma unroll
        for (int e = 0; e < EE; ++e) {
            float v = (e == i1) ? p[i1] : ((e == i2) ? p[i2] : 0.f);
            out[b * EE + e] = v;
        }
        // indices [B,2] as numeric values
        out[64 + b * 2 + 0] = (float)i1;
        out[64 + b * 2 + 1] = (float)i2;
        // topk gate scores [B,2]
        out[80 + b * 2 + 0] = p[i1];
        out[80 + b * 2 + 1] = p[i2];
    }
}

extern "C" void kernel_launch(void* const* d_in, const int* in_sizes, int n_in,
                              void* d_out, int out_size, void* d_ws, size_t ws_size,
                              hipStream_t stream) {
    const float* x     = (const float*)d_in[0];
    const float* W     = (const float*)d_in[1];
    const float* gain  = (const float*)d_in[2];
    const float* istd  = (const float*)d_in[3];
    const float* noise = (const float*)d_in[4];
    // d_in[5] = top_k (==2) — hardcoded per reference.

    float* pbuf = (float*)d_ws;          // NBLK*9 + 16 floats ~= 74 KB
    float* out  = (float*)d_out;         // 96 fp32

    k_partial<<<dim3(NBLK), dim3(256), 0, stream>>>(x, W, pbuf);
    k_finish<<<dim3(1), dim3(256), 0, stream>>>(pbuf, gain, istd, noise, out);
}